// Round 5
// baseline (159.596 us; speedup 1.0000x reference)
//
#include <hip/hip_runtime.h>
#include <hip/hip_bf16.h>

#define N_NODES 50000
#define NE      800000
#define NT32    (NE / 32)
#define NTILES  (NE / 16)

typedef __attribute__((ext_vector_type(8)))  short bf16x8;
typedef __attribute__((ext_vector_type(4)))  float f32x4;
typedef __attribute__((ext_vector_type(16))) float f32x16;
typedef __attribute__((ext_vector_type(4)))  int   i32x4;
typedef __attribute__((ext_vector_type(2)))  int   i32x2;

static __device__ __forceinline__ short f2bf(float x) {
    union { float f; unsigned u; } v; v.f = x;
    unsigned r = (v.u + 0x7fffu + ((v.u >> 16) & 1u)) >> 16;  // RNE
    return (short)r;
}
static __device__ __forceinline__ float bflo(unsigned u) {
    union { unsigned u; float f; } v; v.u = u << 16; return v.f;
}
static __device__ __forceinline__ float bfhi(unsigned u) {
    union { unsigned u; float f; } v; v.u = u & 0xffff0000u; return v.f;
}
static __device__ __forceinline__ float bfs(unsigned short u) {
    union { unsigned u; float f; } v; v.u = ((unsigned)u) << 16; return v.f;
}
static __device__ __forceinline__ unsigned pk2bf(float a, float b) {
    // hardware v_cvt_pk_bf16_f32 via HIP API (m240: API, not hand-asm)
    union { __hip_bfloat162 h; unsigned u; } v;
    float2 f; f.x = a; f.y = b;
    v.h = __float22bfloat162_rn(f);
    return v.u;
}

// ---- workspace image layout (bytes from WF base) ----
#define OFF_W2   32768
#define OFF_B1   49152
#define OFF_B2   49408
#define OFF_GT1  49536
#define OFF_GT2  50048
#define OFF_W3   50304
#define IMG_B    50432
#define IMG_V4   (IMG_B / 16)   // 3152

// ---------------- prep A: pack emb + weight images ----------------

__global__ void pack_consts(const float* __restrict__ emb,
                            const float* __restrict__ W1, const float* __restrict__ b1,
                            const float* __restrict__ g1, const float* __restrict__ bt1,
                            const float* __restrict__ W2, const float* __restrict__ b2,
                            const float* __restrict__ g2, const float* __restrict__ bt2,
                            const float* __restrict__ W3,
                            ushort* __restrict__ embB, char* __restrict__ img)
{
    const int i0 = blockIdx.x * 256 + threadIdx.x;
    const int n  = gridDim.x * 256;

    for (int t = i0; t < (N_NODES * 64 / 8); t += n) {
        const f32x4* p = (const f32x4*)(emb + (size_t)t * 8);
        f32x4 a = p[0], b = p[1];
        unsigned u0 = pk2bf(a[0], a[1]);
        unsigned u1 = pk2bf(a[2], a[3]);
        unsigned u2 = pk2bf(b[0], b[1]);
        unsigned u3 = pk2bf(b[2], b[3]);
        i32x4 o = {(int)u0, (int)u1, (int)u2, (int)u3};
        *(i32x4*)(embB + (size_t)t * 8) = o;
    }
    ushort* W1f = (ushort*)img;
    for (int t = i0; t < 16384; t += n) {
        int j = t & 7, lane = (t >> 3) & 63, f = t >> 9;
        int mt = f >> 3, ke = f & 7, h = lane >> 5, c = lane & 31;
        W1f[t] = f2bf(W1[(16 * ke + 8 * h + j) * 128 + 32 * mt + c]);
    }
    ushort* W2f = (ushort*)(img + OFF_W2);
    for (int t = i0; t < 8192; t += n) {
        int j = t & 7, lane = (t >> 3) & 63, f = t >> 9;
        int mt = f >> 3, ke = f & 7, h = lane >> 5, c = lane & 31;
        W2f[t] = f2bf(W2[(16 * ke + 8 * h + j) * 64 + 32 * mt + c]);
    }
    if (i0 < 128) ((ushort*)(img + OFF_B1))[i0] = f2bf(b1[i0]);
    if (i0 < 64)  ((ushort*)(img + OFF_B2))[i0] = f2bf(b2[i0]);
    if (i0 < 128) {
        int r4 = i0 & 3, h = (i0 >> 2) & 1, q4 = (i0 >> 3) & 3, mt = i0 >> 5;
        int f = 32 * mt + 8 * q4 + 4 * h + r4;
        ((unsigned*)(img + OFF_GT1))[i0] =
            (unsigned)(ushort)f2bf(g1[f]) | ((unsigned)(ushort)f2bf(bt1[f]) << 16);
    }
    if (i0 < 64) {
        int r4 = i0 & 3, h = (i0 >> 2) & 1, q4 = (i0 >> 3) & 3, mt = i0 >> 5;
        int f = 32 * mt + 8 * q4 + 4 * h + r4;
        ((unsigned*)(img + OFF_GT2))[i0] =
            (unsigned)(ushort)f2bf(g2[f]) | ((unsigned)(ushort)f2bf(bt2[f]) << 16);
        ((ushort*)(img + OFF_W3))[i0] = f2bf(W3[f]);
    }
}

// ---------------- prep B: degree histogram ----------------

__global__ void degree_hist(const int* __restrict__ src, const int* __restrict__ dst,
                            int* __restrict__ outd, int* __restrict__ ind) {
    int i = blockIdx.x * 256 + threadIdx.x;
    if (i < NE) {
        atomicAdd(outd + src[i], 1);
        atomicAdd(ind + dst[i], 1);
    }
}

// ---------------- main: 32x32x16 MFMA, transposed (features=M, edges=N) ----------------
// A (weights): lane l holds A[l&31][(l>>5)*8+j]
// B (data):    lane l holds B[(l>>5)*8+j][l&31]
// C: col=lane&31 (edge), row=(reg&3)+8*(reg>>2)+4*(lane>>5) (feature) [m74/m101]
// 1-deep software pipeline: next-tile indices issued at loop top, next-tile
// emb fragments issued after mt=0,1 retire (register headroom), epilogue
// loads (noise/degree) issued at loop top.

__global__ __launch_bounds__(256, 3) void edge_mlp32(
    const ushort* __restrict__ embB,
    const int*   __restrict__ src, const int* __restrict__ dst,
    const float* __restrict__ noise,
    const i32x4* __restrict__ WFimg,
    const float* __restrict__ b3p,
    const int* __restrict__ outd, const int* __restrict__ ind,
    float* __restrict__ out)
{
    __shared__ i32x4 ldsv[IMG_V4];
    char* ldsb = (char*)ldsv;

    const int tid = threadIdx.x;
    for (int i = tid; i < IMG_V4; i += 256) ldsv[i] = WFimg[i];
    __syncthreads();

    const int wid = tid >> 6;
    const int l   = tid & 63;
    const int h   = l >> 5;
    const int c   = l & 31;

    const float b3v = b3p[0];

    bf16x8 bone = {};
    bone[0] = (h == 0) ? (short)0x3F80 : (short)0;

    const int gw = blockIdx.x * 4 + wid;
    const int nw = gridDim.x * 4;

    // ---- pipeline prologue: indices + fragments for first tile ----
    int sn, dn;
    bf16x8 fA0, fA1, fA2, fA3, fB0, fB1, fB2, fB3;
    {
        int t0 = (gw < NT32) ? gw : (NT32 - 1);
        int e0p = t0 * 32 + c;
        sn = src[e0p]; dn = dst[e0p];
        const ushort* sp = embB + (size_t)sn * 64;
        const ushort* dp = embB + (size_t)dn * 64;
        fA0 = *(const bf16x8*)(sp + 8 * h);
        fA1 = *(const bf16x8*)(sp + 16 + 8 * h);
        fA2 = *(const bf16x8*)(sp + 32 + 8 * h);
        fA3 = *(const bf16x8*)(sp + 48 + 8 * h);
        fB0 = *(const bf16x8*)(dp + 8 * h);
        fB1 = *(const bf16x8*)(dp + 16 + 8 * h);
        fB2 = *(const bf16x8*)(dp + 32 + 8 * h);
        fB3 = *(const bf16x8*)(dp + 48 + 8 * h);
    }

    for (int tile = gw; tile < NT32; tile += nw) {
        unsigned tz;
        asm volatile("v_mov_b32 %0, 0" : "=v"(tz));   // anti-LICM anchor
        const char* ldz = ldsb + tz;

        const int e0 = tile * 32 + c;

        // ---- issue next-tile index loads + current-tile epilogue loads ----
        const int tn  = tile + nw;
        const int tcl = (tn < NT32) ? tn : tile;
        const int e0n = tcl * 32 + c;
        int snN = src[e0n];
        int dnN = dst[e0n];
        float nz = noise[e0];
        int odv = outd[sn];
        int idv = ind[dn];

        // ---- layer 1 MFMAs (consume prefetched frags) ----
        const ushort* W1z = (const ushort*)ldz;
        f32x16 acc[4] = {};
        {
            bf16x8 bfr[8] = {fA0, fA1, fA2, fA3, fB0, fB1, fB2, fB3};
#pragma unroll
            for (int ke = 0; ke < 8; ++ke) {
#pragma unroll
                for (int mt = 0; mt < 4; ++mt) {
                    bf16x8 w = *(const bf16x8*)(W1z + (mt * 8 + ke) * 512 + l * 8);
                    acc[mt] = __builtin_amdgcn_mfma_f32_32x32x16_bf16(w, bfr[ke], acc[mt], 0, 0, 0);
                }
            }
        }
        // b1 fold
        const ushort* b1z = (const ushort*)(ldz + OFF_B1);
#pragma unroll
        for (int mt = 0; mt < 4; ++mt) {
            bf16x8 w = {};
            short bv = b1z[32 * mt + c];
            w[0] = (h == 0) ? bv : (short)0;
            acc[mt] = __builtin_amdgcn_mfma_f32_32x32x16_bf16(w, bone, acc[mt], 0, 0, 0);
        }

        // ---- LN1 stats ----
        float s0 = 0.f, s1 = 0.f, q0 = 0.f, q1 = 0.f;
#pragma unroll
        for (int mt = 0; mt < 4; ++mt) {
#pragma unroll
            for (int i = 0; i < 16; i += 2) {
                float v0 = acc[mt][i], v1 = acc[mt][i + 1];
                s0 += v0; q0 = fmaf(v0, v0, q0);
                s1 += v1; q1 = fmaf(v1, v1, q1);
            }
        }
        float s = s0 + s1, q = q0 + q1;
        s += __shfl_xor(s, 32);
        q += __shfl_xor(q, 32);
        const float mu = s * (1.0f / 128.0f);
        const float rs = rsqrtf(q * (1.0f / 128.0f) - mu * mu + 1e-5f);
        const float c0 = -mu * rs;

        // ---- per-mt: LN1 apply+pack -> cross-h exchange -> layer-2 MFMAs ----
        const ushort* W2z = (const ushort*)(ldz + OFF_W2);
        f32x16 acc2[2] = {};
#pragma unroll
        for (int mt = 0; mt < 4; ++mt) {
            unsigned pk[4][2];
#pragma unroll
            for (int q4 = 0; q4 < 4; ++q4) {
                i32x4 pg = *(const i32x4*)(ldz + OFF_GT1 + ((mt * 4 + q4) * 2 + h) * 16);
                float t[4];
#pragma unroll
                for (int r4 = 0; r4 < 4; ++r4) {
                    unsigned u = (unsigned)pg[r4];
                    float v = acc[mt][q4 * 4 + r4];
                    float w = fmaf(v, rs, c0);
                    float y = fmaf(w, bflo(u), bfhi(u));
                    t[r4] = fmaxf(y, 0.f);
                }
                pk[q4][0] = pk2bf(t[0], t[1]);
                pk[q4][1] = pk2bf(t[2], t[3]);
            }
#pragma unroll
            for (int sub = 0; sub < 2; ++sub) {
                const int ke = 2 * mt + sub;
                const int qa = 2 * sub, qb = qa + 1;
                unsigned S0 = h ? pk[qa][0] : pk[qb][0];
                unsigned S1 = h ? pk[qa][1] : pk[qb][1];
                unsigned r0 = (unsigned)__shfl_xor((int)S0, 32);
                unsigned r1 = (unsigned)__shfl_xor((int)S1, 32);
                unsigned o0 = h ? pk[qb][0] : pk[qa][0];
                unsigned o1 = h ? pk[qb][1] : pk[qa][1];
                union { i32x4 i; bf16x8 b; } u;
                u.i[0] = (int)(h ? r0 : o0);
                u.i[1] = (int)(h ? r1 : o1);
                u.i[2] = (int)(h ? o0 : r0);
                u.i[3] = (int)(h ? o1 : r1);
#pragma unroll
                for (int mt2 = 0; mt2 < 2; ++mt2) {
                    bf16x8 w = *(const bf16x8*)(W2z + (mt2 * 8 + ke) * 512 + l * 8);
                    acc2[mt2] = __builtin_amdgcn_mfma_f32_32x32x16_bf16(w, u.b, acc2[mt2], 0, 0, 0);
                }
            }
            // ---- after mt=1 retires (acc[0..1] dead): issue next-tile gathers ----
            if (mt == 1) {
                const ushort* spn = embB + (size_t)snN * 64;
                const ushort* dpn = embB + (size_t)dnN * 64;
                fA0 = *(const bf16x8*)(spn + 8 * h);
                fA1 = *(const bf16x8*)(spn + 16 + 8 * h);
                fA2 = *(const bf16x8*)(spn + 32 + 8 * h);
                fA3 = *(const bf16x8*)(spn + 48 + 8 * h);
                fB0 = *(const bf16x8*)(dpn + 8 * h);
                fB1 = *(const bf16x8*)(dpn + 16 + 8 * h);
                fB2 = *(const bf16x8*)(dpn + 32 + 8 * h);
                fB3 = *(const bf16x8*)(dpn + 48 + 8 * h);
            }
        }
        const ushort* b2z = (const ushort*)(ldz + OFF_B2);
#pragma unroll
        for (int mt2 = 0; mt2 < 2; ++mt2) {
            bf16x8 w = {};
            short bv = b2z[32 * mt2 + c];
            w[0] = (h == 0) ? bv : (short)0;
            acc2[mt2] = __builtin_amdgcn_mfma_f32_32x32x16_bf16(w, bone, acc2[mt2], 0, 0, 0);
        }

        // ---- LN2 stats ----
        float t0 = 0.f, t1 = 0.f, p0 = 0.f, p1 = 0.f;
#pragma unroll
        for (int mt2 = 0; mt2 < 2; ++mt2) {
#pragma unroll
            for (int i = 0; i < 16; i += 2) {
                float v0 = acc2[mt2][i], v1 = acc2[mt2][i + 1];
                t0 += v0; p0 = fmaf(v0, v0, p0);
                t1 += v1; p1 = fmaf(v1, v1, p1);
            }
        }
        float s2 = t0 + t1, q2 = p0 + p1;
        s2 += __shfl_xor(s2, 32);
        q2 += __shfl_xor(q2, 32);
        const float mu2 = s2 * (1.0f / 64.0f);
        const float rs2 = rsqrtf(q2 * (1.0f / 64.0f) - mu2 * mu2 + 1e-5f);
        const float c02 = -mu2 * rs2;

        // ---- LN2 apply + relu + dot(W3) ----
        float lg = 0.f;
#pragma unroll
        for (int mt2 = 0; mt2 < 2; ++mt2) {
#pragma unroll
            for (int q4 = 0; q4 < 4; ++q4) {
                const int bse = (mt2 * 4 + q4) * 2 + h;
                i32x4 pg = *(const i32x4*)(ldz + OFF_GT2 + bse * 16);
                i32x2 wq = *(const i32x2*)(ldz + OFF_W3 + bse * 8);
#pragma unroll
                for (int r4 = 0; r4 < 4; ++r4) {
                    unsigned ug = (unsigned)pg[r4];
                    unsigned short uw = (unsigned short)(((unsigned)wq[r4 >> 1]) >> (16 * (r4 & 1)));
                    float v = acc2[mt2][q4 * 4 + r4];
                    float w = fmaf(v, rs2, c02);
                    float y = fmaf(w, bflo(ug), bfhi(ug));
                    y = fmaxf(y, 0.f);
                    lg = fmaf(y, bfs(uw), lg);
                }
            }
        }
        lg += __shfl_xor(lg, 32);
        lg += b3v;

        // ---- gate + degree norm (h==0 lanes), using preloaded nz/odv/idv ----
        if (h == 0) {
            float z = __logf(nz) - log1pf(-nz) + lg;
            float gate = 1.0f / (1.0f + __expf(-z));
            int od = odv; if (od < 1) od = 1;
            int idg = idv; if (idg < 1) idg = 1;
            out[e0] = gate * (rsqrtf((float)od) * rsqrtf((float)idg));
        }

        sn = snN; dn = dnN;
    }
}

// ================= R2 fallback (validated) — used if ws too small =================

__global__ __launch_bounds__(256, 2) void edge_mlp_mfma(
    const float* __restrict__ emb,
    const int*   __restrict__ src, const int* __restrict__ dst,
    const float* __restrict__ noise,
    const float* __restrict__ W1, const float* __restrict__ b1,
    const float* __restrict__ g1, const float* __restrict__ bt1,
    const float* __restrict__ W2, const float* __restrict__ b2,
    const float* __restrict__ g2, const float* __restrict__ bt2,
    const float* __restrict__ W3, const float* __restrict__ b3,
    const int*   __restrict__ outd, const int* __restrict__ ind,
    float* __restrict__ out)
{
    __shared__ short lds[32768];
    const int tid = threadIdx.x;
    const int wid = tid >> 6;
    const int l   = tid & 63;
    const int g   = l >> 4;
    const int c   = l & 15;

    for (int i = tid; i < 16384; i += 256) {
        int j = i & 7, lane = (i >> 3) & 63, p = i >> 9;
        int ks = p >> 3, t = p & 7;
        int row = ks * 32 + (lane >> 4) * 8 + j;
        int col = t * 16 + (lane & 15);
        lds[i] = f2bf(W1[row * 128 + col]);
    }
    for (int i = tid; i < 8192; i += 256) {
        int j = i & 7, lane = (i >> 3) & 63, p = i >> 9;
        int ks = p >> 2, t = p & 3;
        int row = ks * 32 + (lane >> 4) * 8 + j;
        int col = t * 16 + (lane & 15);
        lds[16384 + i] = f2bf(W2[row * 64 + col]);
    }
    __syncthreads();

    short* Hl = lds + 24576 + wid * 2048;
    float b1v[8], g1v[8], t1v[8];
#pragma unroll
    for (int t = 0; t < 8; ++t) { int f = t * 16 + c; b1v[t] = b1[f]; g1v[t] = g1[f]; t1v[t] = bt1[f]; }
    float b2v[4], g2v[4], t2v[4], w3v[4];
#pragma unroll
    for (int t = 0; t < 4; ++t) { int f = t * 16 + c; b2v[t] = b2[f]; g2v[t] = g2[f]; t2v[t] = bt2[f]; w3v[t] = W3[f]; }
    const float b3v = b3[0];

    const int gw = blockIdx.x * 4 + wid;
    const int nw = gridDim.x * 4;

    for (int tile = gw; tile < NTILES; tile += nw) {
        const int e0 = tile * 16 + c;
        const int sn = src[e0], dn = dst[e0];
        const f32x4* sp = (const f32x4*)(emb + (size_t)sn * 64);
        const f32x4* dp = (const f32x4*)(emb + (size_t)dn * 64);
        f32x4 u[8];
        u[0] = sp[2 * g]; u[1] = sp[2 * g + 1];
        u[2] = sp[8 + 2 * g]; u[3] = sp[8 + 2 * g + 1];
        u[4] = dp[2 * g]; u[5] = dp[2 * g + 1];
        u[6] = dp[8 + 2 * g]; u[7] = dp[8 + 2 * g + 1];

        bf16x8 a1[4];
#pragma unroll
        for (int ks = 0; ks < 4; ++ks) {
            f32x4 x0 = u[2 * ks], x1 = u[2 * ks + 1];
            bf16x8 a;
            a[0] = f2bf(x0[0]); a[1] = f2bf(x0[1]); a[2] = f2bf(x0[2]); a[3] = f2bf(x0[3]);
            a[4] = f2bf(x1[0]); a[5] = f2bf(x1[1]); a[6] = f2bf(x1[2]); a[7] = f2bf(x1[3]);
            a1[ks] = a;
        }
        f32x4 acc1[8];
#pragma unroll
        for (int t = 0; t < 8; ++t) { f32x4 z = {b1v[t], b1v[t], b1v[t], b1v[t]}; acc1[t] = z; }
#pragma unroll
        for (int ks = 0; ks < 4; ++ks) {
#pragma unroll
            for (int t = 0; t < 8; ++t) {
                bf16x8 b = *(const bf16x8*)(lds + (ks * 8 + t) * 512 + l * 8);
                acc1[t] = __builtin_amdgcn_mfma_f32_16x16x32_bf16(a1[ks], b, acc1[t], 0, 0, 0);
            }
        }
        float mean[4], rstd[4];
#pragma unroll
        for (int r = 0; r < 4; ++r) {
            float s = acc1[0][r];
#pragma unroll
            for (int t = 1; t < 8; ++t) s += acc1[t][r];
            s += __shfl_xor(s, 1); s += __shfl_xor(s, 2);
            s += __shfl_xor(s, 4); s += __shfl_xor(s, 8);
            float m = s * (1.0f / 128.0f);
            float q = 0.f;
#pragma unroll
            for (int t = 0; t < 8; ++t) { float d = acc1[t][r] - m; q = fmaf(d, d, q); }
            q += __shfl_xor(q, 1); q += __shfl_xor(q, 2);
            q += __shfl_xor(q, 4); q += __shfl_xor(q, 8);
            mean[r] = m; rstd[r] = rsqrtf(q * (1.0f / 128.0f) + 1e-5f);
        }
#pragma unroll
        for (int r = 0; r < 4; ++r) {
            int rw = g * 4 + r;
            int swz = (rw & 7) << 3;
#pragma unroll
            for (int t = 0; t < 8; ++t) {
                float y = fmaf((acc1[t][r] - mean[r]) * rstd[r], g1v[t], t1v[t]);
                y = fmaxf(y, 0.f);
                Hl[rw * 128 + ((t * 16 + c) ^ swz)] = f2bf(y);
            }
        }
        bf16x8 a2[4];
        const int swzr = (c & 7) << 3;
#pragma unroll
        for (int ks = 0; ks < 4; ++ks)
            a2[ks] = *(const bf16x8*)(Hl + c * 128 + ((ks * 32 + g * 8) ^ swzr));

        f32x4 acc2[4];
#pragma unroll
        for (int t = 0; t < 4; ++t) { f32x4 z = {b2v[t], b2v[t], b2v[t], b2v[t]}; acc2[t] = z; }
#pragma unroll
        for (int ks = 0; ks < 4; ++ks) {
#pragma unroll
            for (int t = 0; t < 4; ++t) {
                bf16x8 b = *(const bf16x8*)(lds + 16384 + (ks * 4 + t) * 512 + l * 8);
                acc2[t] = __builtin_amdgcn_mfma_f32_16x16x32_bf16(a2[ks], b, acc2[t], 0, 0, 0);
            }
        }
        float logit[4];
#pragma unroll
        for (int r = 0; r < 4; ++r) {
            float s = acc2[0][r] + acc2[1][r] + acc2[2][r] + acc2[3][r];
            s += __shfl_xor(s, 1); s += __shfl_xor(s, 2);
            s += __shfl_xor(s, 4); s += __shfl_xor(s, 8);
            float m = s * (1.0f / 64.0f);
            float q = 0.f;
#pragma unroll
            for (int t = 0; t < 4; ++t) { float d = acc2[t][r] - m; q = fmaf(d, d, q); }
            q += __shfl_xor(q, 1); q += __shfl_xor(q, 2);
            q += __shfl_xor(q, 4); q += __shfl_xor(q, 8);
            float rs = rsqrtf(q * (1.0f / 64.0f) + 1e-5f);
            float p = 0.f;
#pragma unroll
            for (int t = 0; t < 4; ++t) {
                float y = fmaf((acc2[t][r] - m) * rs, g2v[t], t2v[t]);
                y = fmaxf(y, 0.f);
                p = fmaf(y, w3v[t], p);
            }
            p += __shfl_xor(p, 1); p += __shfl_xor(p, 2);
            p += __shfl_xor(p, 4); p += __shfl_xor(p, 8);
            logit[r] = p + b3v;
        }
        if (c < 4) {
            int e = tile * 16 + g * 4 + c;
            float lg = (c == 0) ? logit[0] : (c == 1) ? logit[1] : (c == 2) ? logit[2] : logit[3];
            float nz = noise[e];
            float z = __logf(nz) - log1pf(-nz) + lg;
            float gate = 1.0f / (1.0f + __expf(-z));
            int od = outd[src[e]]; if (od < 1) od = 1;
            int idg = ind[dst[e]]; if (idg < 1) idg = 1;
            out[e] = gate * (rsqrtf((float)od) * rsqrtf((float)idg));
        }
    }
}

// ---------------- launch ----------------

extern "C" void kernel_launch(void* const* d_in, const int* in_sizes, int n_in,
                              void* d_out, int out_size, void* d_ws, size_t ws_size,
                              hipStream_t stream) {
    const float* emb   = (const float*)d_in[0];
    const int*   src   = (const int*)  d_in[1];
    const int*   dst   = (const int*)  d_in[2];
    const float* noise = (const float*)d_in[3];
    const float* W1  = (const float*)d_in[4];
    const float* b1  = (const float*)d_in[5];
    const float* g1  = (const float*)d_in[6];
    const float* bt1 = (const float*)d_in[7];
    const float* W2  = (const float*)d_in[8];
    const float* b2  = (const float*)d_in[9];
    const float* g2  = (const float*)d_in[10];
    const float* bt2 = (const float*)d_in[11];
    const float* W3  = (const float*)d_in[12];
    const float* b3  = (const float*)d_in[13];

    char* ws = (char*)d_ws;
    const size_t NEED = 6400000 + IMG_B + 400000;

    if (ws_size >= NEED) {
        ushort* embB = (ushort*)ws;                       // 6,400,000 B
        char*   img  = ws + 6400000;                      // 50,432 B
        int* outd = (int*)(ws + 6400000 + IMG_B);
        int* ind  = outd + N_NODES;

        hipMemsetAsync(outd, 0, 2 * N_NODES * sizeof(int), stream);
        pack_consts<<<1024, 256, 0, stream>>>(emb, W1, b1, g1, bt1,
                                              W2, b2, g2, bt2, W3, embB, img);
        degree_hist<<<(NE + 255) / 256, 256, 0, stream>>>(src, dst, outd, ind);
        edge_mlp32<<<768, 256, 0, stream>>>(embB, src, dst, noise, (const i32x4*)img,
                                            b3, outd, ind, (float*)d_out);
    } else {
        int* outd = (int*)ws;
        int* ind  = outd + N_NODES;
        hipMemsetAsync(outd, 0, 2 * N_NODES * sizeof(int), stream);
        degree_hist<<<(NE + 255) / 256, 256, 0, stream>>>(src, dst, outd, ind);
        edge_mlp_mfma<<<512, 256, 0, stream>>>(emb, src, dst, noise,
                                               W1, b1, g1, bt1,
                                               W2, b2, g2, bt2,
                                               W3, b3, outd, ind,
                                               (float*)d_out);
    }
}

// Round 6
// 156.043 us; speedup vs baseline: 1.0228x; 1.0228x over previous
//
#include <hip/hip_runtime.h>
#include <hip/hip_bf16.h>

#define N_NODES 50000
#define NE      800000
#define NT32    (NE / 32)
#define NTILES  (NE / 16)

typedef __attribute__((ext_vector_type(8)))  short bf16x8;
typedef __attribute__((ext_vector_type(4)))  float f32x4;
typedef __attribute__((ext_vector_type(16))) float f32x16;
typedef __attribute__((ext_vector_type(4)))  int   i32x4;
typedef __attribute__((ext_vector_type(2)))  int   i32x2;

static __device__ __forceinline__ short f2bf(float x) {
    union { float f; unsigned u; } v; v.f = x;
    unsigned r = (v.u + 0x7fffu + ((v.u >> 16) & 1u)) >> 16;  // RNE
    return (short)r;
}
static __device__ __forceinline__ float bflo(unsigned u) {
    union { unsigned u; float f; } v; v.u = u << 16; return v.f;
}
static __device__ __forceinline__ float bfhi(unsigned u) {
    union { unsigned u; float f; } v; v.u = u & 0xffff0000u; return v.f;
}
static __device__ __forceinline__ float bfs(unsigned short u) {
    union { unsigned u; float f; } v; v.u = ((unsigned)u) << 16; return v.f;
}
static __device__ __forceinline__ unsigned pk2bf(float a, float b) {
    union { __hip_bfloat162 h; unsigned u; } v;
    float2 f; f.x = a; f.y = b;
    v.h = __float22bfloat162_rn(f);
    return v.u;
}

// ---- workspace image layout (bytes from WF base) ----
#define OFF_W2   32768
#define OFF_B1   49152
#define OFF_B2   49408
#define OFF_GT1  49536
#define OFF_GT2  50048
#define OFF_W3   50304
#define IMG_B    50432
#define IMG_V4   (IMG_B / 16)   // 3152

// ---------------- fused prep: pack emb + weight images + degree hist ----------------

__global__ void prep_hist(const float* __restrict__ emb,
                          const int* __restrict__ src, const int* __restrict__ dst,
                          const float* __restrict__ W1, const float* __restrict__ b1,
                          const float* __restrict__ g1, const float* __restrict__ bt1,
                          const float* __restrict__ W2, const float* __restrict__ b2,
                          const float* __restrict__ g2, const float* __restrict__ bt2,
                          const float* __restrict__ W3,
                          ushort* __restrict__ embB, char* __restrict__ img,
                          int* __restrict__ outd, int* __restrict__ ind)
{
    const int i0 = blockIdx.x * 256 + threadIdx.x;
    const int n  = gridDim.x * 256;

    for (int t = i0; t < (N_NODES * 64 / 8); t += n) {
        const f32x4* p = (const f32x4*)(emb + (size_t)t * 8);
        f32x4 a = p[0], b = p[1];
        unsigned u0 = pk2bf(a[0], a[1]);
        unsigned u1 = pk2bf(a[2], a[3]);
        unsigned u2 = pk2bf(b[0], b[1]);
        unsigned u3 = pk2bf(b[2], b[3]);
        i32x4 o = {(int)u0, (int)u1, (int)u2, (int)u3};
        *(i32x4*)(embB + (size_t)t * 8) = o;
    }
    for (int t = i0; t < NE; t += n) {
        atomicAdd(outd + src[t], 1);
        atomicAdd(ind + dst[t], 1);
    }
    ushort* W1f = (ushort*)img;
    for (int t = i0; t < 16384; t += n) {
        int j = t & 7, lane = (t >> 3) & 63, f = t >> 9;
        int mt = f >> 3, ke = f & 7, h = lane >> 5, c = lane & 31;
        W1f[t] = f2bf(W1[(16 * ke + 8 * h + j) * 128 + 32 * mt + c]);
    }
    ushort* W2f = (ushort*)(img + OFF_W2);
    for (int t = i0; t < 8192; t += n) {
        int j = t & 7, lane = (t >> 3) & 63, f = t >> 9;
        int mt = f >> 3, ke = f & 7, h = lane >> 5, c = lane & 31;
        W2f[t] = f2bf(W2[(16 * ke + 8 * h + j) * 64 + 32 * mt + c]);
    }
    if (i0 < 128) ((ushort*)(img + OFF_B1))[i0] = f2bf(b1[i0]);
    if (i0 < 64)  ((ushort*)(img + OFF_B2))[i0] = f2bf(b2[i0]);
    if (i0 < 128) {
        int r4 = i0 & 3, h = (i0 >> 2) & 1, q4 = (i0 >> 3) & 3, mt = i0 >> 5;
        int f = 32 * mt + 8 * q4 + 4 * h + r4;
        ((unsigned*)(img + OFF_GT1))[i0] =
            (unsigned)(ushort)f2bf(g1[f]) | ((unsigned)(ushort)f2bf(bt1[f]) << 16);
    }
    if (i0 < 64) {
        int r4 = i0 & 3, h = (i0 >> 2) & 1, q4 = (i0 >> 3) & 3, mt = i0 >> 5;
        int f = 32 * mt + 8 * q4 + 4 * h + r4;
        ((unsigned*)(img + OFF_GT2))[i0] =
            (unsigned)(ushort)f2bf(g2[f]) | ((unsigned)(ushort)f2bf(bt2[f]) << 16);
        ((ushort*)(img + OFF_W3))[i0] = f2bf(W3[f]);
    }
}

// ---------------- main: 32x32x16 MFMA, transposed (features=M, edges=N) ----------------
// A (weights): lane l holds A[l&31][(l>>5)*8+j]
// B (data):    lane l holds B[(l>>5)*8+j][l&31]
// C: col=lane&31 (edge), row=(reg&3)+8*(reg>>2)+4*(lane>>5) (feature) [m74/m101]
// Register budget: unified VGPR+AGPR file; acc(64)+acc2(32) live peak must stay
// <=170 total for 3 waves/SIMD (launch_bounds(256,3)). Next-tile gathers are
// issued AFTER the b2-fold, where acc[] is dead (peak ~= acc2+frags+misc).

__global__ __launch_bounds__(256, 3) void edge_mlp32(
    const ushort* __restrict__ embB,
    const int*   __restrict__ src, const int* __restrict__ dst,
    const float* __restrict__ noise,
    const i32x4* __restrict__ WFimg,
    const float* __restrict__ b3p,
    const int* __restrict__ outd, const int* __restrict__ ind,
    float* __restrict__ out)
{
    __shared__ i32x4 ldsv[IMG_V4];
    char* ldsb = (char*)ldsv;

    const int tid = threadIdx.x;
    for (int i = tid; i < IMG_V4; i += 256) ldsv[i] = WFimg[i];
    __syncthreads();

    const int wid = tid >> 6;
    const int l   = tid & 63;
    const int h   = l >> 5;
    const int c   = l & 31;

    const float b3v = b3p[0];

    bf16x8 bone = {};
    bone[0] = (h == 0) ? (short)0x3F80 : (short)0;

    const int gw = blockIdx.x * 4 + wid;
    const int nw = gridDim.x * 4;

    // ---- pipeline prologue: indices + fragments for first tile ----
    int sn, dn;
    bf16x8 fA0, fA1, fA2, fA3, fB0, fB1, fB2, fB3;
    {
        int t0 = (gw < NT32) ? gw : (NT32 - 1);
        int e0p = t0 * 32 + c;
        sn = src[e0p]; dn = dst[e0p];
        const ushort* sp = embB + (size_t)sn * 64;
        const ushort* dp = embB + (size_t)dn * 64;
        fA0 = *(const bf16x8*)(sp + 8 * h);
        fA1 = *(const bf16x8*)(sp + 16 + 8 * h);
        fA2 = *(const bf16x8*)(sp + 32 + 8 * h);
        fA3 = *(const bf16x8*)(sp + 48 + 8 * h);
        fB0 = *(const bf16x8*)(dp + 8 * h);
        fB1 = *(const bf16x8*)(dp + 16 + 8 * h);
        fB2 = *(const bf16x8*)(dp + 32 + 8 * h);
        fB3 = *(const bf16x8*)(dp + 48 + 8 * h);
    }

    for (int tile = gw; tile < NT32; tile += nw) {
        unsigned tz;
        asm volatile("v_mov_b32 %0, 0" : "=v"(tz));   // anti-LICM anchor
        const char* ldz = ldsb + tz;

        const int e0 = tile * 32 + c;

        // ---- issue next-tile index loads + current-tile epilogue loads ----
        const int tn  = tile + nw;
        const int tcl = (tn < NT32) ? tn : tile;
        const int e0n = tcl * 32 + c;
        int snN = src[e0n];
        int dnN = dst[e0n];
        float nz = noise[e0];
        int odv = outd[sn];
        int idv = ind[dn];

        // ---- layer 1 MFMAs (consume prefetched frags) ----
        const ushort* W1z = (const ushort*)ldz;
        f32x16 acc[4] = {};
        {
            bf16x8 bfr[8] = {fA0, fA1, fA2, fA3, fB0, fB1, fB2, fB3};
#pragma unroll
            for (int ke = 0; ke < 8; ++ke) {
#pragma unroll
                for (int mt = 0; mt < 4; ++mt) {
                    bf16x8 w = *(const bf16x8*)(W1z + (mt * 8 + ke) * 512 + l * 8);
                    acc[mt] = __builtin_amdgcn_mfma_f32_32x32x16_bf16(w, bfr[ke], acc[mt], 0, 0, 0);
                }
            }
        }
        // b1 fold
        const ushort* b1z = (const ushort*)(ldz + OFF_B1);
#pragma unroll
        for (int mt = 0; mt < 4; ++mt) {
            bf16x8 w = {};
            short bv = b1z[32 * mt + c];
            w[0] = (h == 0) ? bv : (short)0;
            acc[mt] = __builtin_amdgcn_mfma_f32_32x32x16_bf16(w, bone, acc[mt], 0, 0, 0);
        }

        // ---- LN1 stats ----
        float s0 = 0.f, s1 = 0.f, q0 = 0.f, q1 = 0.f;
#pragma unroll
        for (int mt = 0; mt < 4; ++mt) {
#pragma unroll
            for (int i = 0; i < 16; i += 2) {
                float v0 = acc[mt][i], v1 = acc[mt][i + 1];
                s0 += v0; q0 = fmaf(v0, v0, q0);
                s1 += v1; q1 = fmaf(v1, v1, q1);
            }
        }
        float s = s0 + s1, q = q0 + q1;
        s += __shfl_xor(s, 32);
        q += __shfl_xor(q, 32);
        const float mu = s * (1.0f / 128.0f);
        const float rs = rsqrtf(q * (1.0f / 128.0f) - mu * mu + 1e-5f);
        const float c0 = -mu * rs;

        // ---- per-mt: LN1 apply+pack -> cross-h exchange -> layer-2 MFMAs ----
        const ushort* W2z = (const ushort*)(ldz + OFF_W2);
        f32x16 acc2[2] = {};
#pragma unroll
        for (int mt = 0; mt < 4; ++mt) {
            unsigned pk[4][2];
#pragma unroll
            for (int q4 = 0; q4 < 4; ++q4) {
                i32x4 pg = *(const i32x4*)(ldz + OFF_GT1 + ((mt * 4 + q4) * 2 + h) * 16);
                float t[4];
#pragma unroll
                for (int r4 = 0; r4 < 4; ++r4) {
                    unsigned u = (unsigned)pg[r4];
                    float v = acc[mt][q4 * 4 + r4];
                    float w = fmaf(v, rs, c0);
                    float y = fmaf(w, bflo(u), bfhi(u));
                    t[r4] = fmaxf(y, 0.f);
                }
                pk[q4][0] = pk2bf(t[0], t[1]);
                pk[q4][1] = pk2bf(t[2], t[3]);
            }
#pragma unroll
            for (int sub = 0; sub < 2; ++sub) {
                const int ke = 2 * mt + sub;
                const int qa = 2 * sub, qb = qa + 1;
                unsigned S0 = h ? pk[qa][0] : pk[qb][0];
                unsigned S1 = h ? pk[qa][1] : pk[qb][1];
                unsigned r0 = (unsigned)__shfl_xor((int)S0, 32);
                unsigned r1 = (unsigned)__shfl_xor((int)S1, 32);
                unsigned o0 = h ? pk[qb][0] : pk[qa][0];
                unsigned o1 = h ? pk[qb][1] : pk[qa][1];
                union { i32x4 i; bf16x8 b; } u;
                u.i[0] = (int)(h ? r0 : o0);
                u.i[1] = (int)(h ? r1 : o1);
                u.i[2] = (int)(h ? o0 : r0);
                u.i[3] = (int)(h ? o1 : r1);
#pragma unroll
                for (int mt2 = 0; mt2 < 2; ++mt2) {
                    bf16x8 w = *(const bf16x8*)(W2z + (mt2 * 8 + ke) * 512 + l * 8);
                    acc2[mt2] = __builtin_amdgcn_mfma_f32_32x32x16_bf16(w, u.b, acc2[mt2], 0, 0, 0);
                }
            }
        }
        const ushort* b2z = (const ushort*)(ldz + OFF_B2);
#pragma unroll
        for (int mt2 = 0; mt2 < 2; ++mt2) {
            bf16x8 w = {};
            short bv = b2z[32 * mt2 + c];
            w[0] = (h == 0) ? bv : (short)0;
            acc2[mt2] = __builtin_amdgcn_mfma_f32_32x32x16_bf16(w, bone, acc2[mt2], 0, 0, 0);
        }

        // ---- issue next-tile gathers HERE: acc[] dead, register peak minimal ----
        {
            const ushort* spn = embB + (size_t)snN * 64;
            const ushort* dpn = embB + (size_t)dnN * 64;
            fA0 = *(const bf16x8*)(spn + 8 * h);
            fA1 = *(const bf16x8*)(spn + 16 + 8 * h);
            fA2 = *(const bf16x8*)(spn + 32 + 8 * h);
            fA3 = *(const bf16x8*)(spn + 48 + 8 * h);
            fB0 = *(const bf16x8*)(dpn + 8 * h);
            fB1 = *(const bf16x8*)(dpn + 16 + 8 * h);
            fB2 = *(const bf16x8*)(dpn + 32 + 8 * h);
            fB3 = *(const bf16x8*)(dpn + 48 + 8 * h);
        }

        // ---- LN2 stats ----
        float t0 = 0.f, t1 = 0.f, p0 = 0.f, p1 = 0.f;
#pragma unroll
        for (int mt2 = 0; mt2 < 2; ++mt2) {
#pragma unroll
            for (int i = 0; i < 16; i += 2) {
                float v0 = acc2[mt2][i], v1 = acc2[mt2][i + 1];
                t0 += v0; p0 = fmaf(v0, v0, p0);
                t1 += v1; p1 = fmaf(v1, v1, p1);
            }
        }
        float s2 = t0 + t1, q2 = p0 + p1;
        s2 += __shfl_xor(s2, 32);
        q2 += __shfl_xor(q2, 32);
        const float mu2 = s2 * (1.0f / 64.0f);
        const float rs2 = rsqrtf(q2 * (1.0f / 64.0f) - mu2 * mu2 + 1e-5f);
        const float c02 = -mu2 * rs2;

        // ---- LN2 apply + relu + dot(W3) ----
        float lg = 0.f;
#pragma unroll
        for (int mt2 = 0; mt2 < 2; ++mt2) {
#pragma unroll
            for (int q4 = 0; q4 < 4; ++q4) {
                const int bse = (mt2 * 4 + q4) * 2 + h;
                i32x4 pg = *(const i32x4*)(ldz + OFF_GT2 + bse * 16);
                i32x2 wq = *(const i32x2*)(ldz + OFF_W3 + bse * 8);
#pragma unroll
                for (int r4 = 0; r4 < 4; ++r4) {
                    unsigned ug = (unsigned)pg[r4];
                    unsigned short uw = (unsigned short)(((unsigned)wq[r4 >> 1]) >> (16 * (r4 & 1)));
                    float v = acc2[mt2][q4 * 4 + r4];
                    float w = fmaf(v, rs2, c02);
                    float y = fmaf(w, bflo(ug), bfhi(ug));
                    y = fmaxf(y, 0.f);
                    lg = fmaf(y, bfs(uw), lg);
                }
            }
        }
        lg += __shfl_xor(lg, 32);
        lg += b3v;

        // ---- gate + degree norm (h==0 lanes), using preloaded nz/odv/idv ----
        if (h == 0) {
            float z = __logf(nz) - log1pf(-nz) + lg;
            float gate = 1.0f / (1.0f + __expf(-z));
            int od = odv; if (od < 1) od = 1;
            int idg = idv; if (idg < 1) idg = 1;
            out[e0] = gate * (rsqrtf((float)od) * rsqrtf((float)idg));
        }

        sn = snN; dn = dnN;
    }
}

// ================= R2 fallback (validated) — used if ws too small =================

__global__ void degree_hist(const int* __restrict__ src, const int* __restrict__ dst,
                            int* __restrict__ outd, int* __restrict__ ind) {
    int i = blockIdx.x * 256 + threadIdx.x;
    if (i < NE) {
        atomicAdd(outd + src[i], 1);
        atomicAdd(ind + dst[i], 1);
    }
}

__global__ __launch_bounds__(256, 2) void edge_mlp_mfma(
    const float* __restrict__ emb,
    const int*   __restrict__ src, const int* __restrict__ dst,
    const float* __restrict__ noise,
    const float* __restrict__ W1, const float* __restrict__ b1,
    const float* __restrict__ g1, const float* __restrict__ bt1,
    const float* __restrict__ W2, const float* __restrict__ b2,
    const float* __restrict__ g2, const float* __restrict__ bt2,
    const float* __restrict__ W3, const float* __restrict__ b3,
    const int*   __restrict__ outd, const int* __restrict__ ind,
    float* __restrict__ out)
{
    __shared__ short lds[32768];
    const int tid = threadIdx.x;
    const int wid = tid >> 6;
    const int l   = tid & 63;
    const int g   = l >> 4;
    const int c   = l & 15;

    for (int i = tid; i < 16384; i += 256) {
        int j = i & 7, lane = (i >> 3) & 63, p = i >> 9;
        int ks = p >> 3, t = p & 7;
        int row = ks * 32 + (lane >> 4) * 8 + j;
        int col = t * 16 + (lane & 15);
        lds[i] = f2bf(W1[row * 128 + col]);
    }
    for (int i = tid; i < 8192; i += 256) {
        int j = i & 7, lane = (i >> 3) & 63, p = i >> 9;
        int ks = p >> 2, t = p & 3;
        int row = ks * 32 + (lane >> 4) * 8 + j;
        int col = t * 16 + (lane & 15);
        lds[16384 + i] = f2bf(W2[row * 64 + col]);
    }
    __syncthreads();

    short* Hl = lds + 24576 + wid * 2048;
    float b1v[8], g1v[8], t1v[8];
#pragma unroll
    for (int t = 0; t < 8; ++t) { int f = t * 16 + c; b1v[t] = b1[f]; g1v[t] = g1[f]; t1v[t] = bt1[f]; }
    float b2v[4], g2v[4], t2v[4], w3v[4];
#pragma unroll
    for (int t = 0; t < 4; ++t) { int f = t * 16 + c; b2v[t] = b2[f]; g2v[t] = g2[f]; t2v[t] = bt2[f]; w3v[t] = W3[f]; }
    const float b3v = b3[0];

    const int gw = blockIdx.x * 4 + wid;
    const int nw = gridDim.x * 4;

    for (int tile = gw; tile < NTILES; tile += nw) {
        const int e0 = tile * 16 + c;
        const int sn = src[e0], dn = dst[e0];
        const f32x4* sp = (const f32x4*)(emb + (size_t)sn * 64);
        const f32x4* dp = (const f32x4*)(emb + (size_t)dn * 64);
        f32x4 u[8];
        u[0] = sp[2 * g]; u[1] = sp[2 * g + 1];
        u[2] = sp[8 + 2 * g]; u[3] = sp[8 + 2 * g + 1];
        u[4] = dp[2 * g]; u[5] = dp[2 * g + 1];
        u[6] = dp[8 + 2 * g]; u[7] = dp[8 + 2 * g + 1];

        bf16x8 a1[4];
#pragma unroll
        for (int ks = 0; ks < 4; ++ks) {
            f32x4 x0 = u[2 * ks], x1 = u[2 * ks + 1];
            bf16x8 a;
            a[0] = f2bf(x0[0]); a[1] = f2bf(x0[1]); a[2] = f2bf(x0[2]); a[3] = f2bf(x0[3]);
            a[4] = f2bf(x1[0]); a[5] = f2bf(x1[1]); a[6] = f2bf(x1[2]); a[7] = f2bf(x1[3]);
            a1[ks] = a;
        }
        f32x4 acc1[8];
#pragma unroll
        for (int t = 0; t < 8; ++t) { f32x4 z = {b1v[t], b1v[t], b1v[t], b1v[t]}; acc1[t] = z; }
#pragma unroll
        for (int ks = 0; ks < 4; ++ks) {
#pragma unroll
            for (int t = 0; t < 8; ++t) {
                bf16x8 b = *(const bf16x8*)(lds + (ks * 8 + t) * 512 + l * 8);
                acc1[t] = __builtin_amdgcn_mfma_f32_16x16x32_bf16(a1[ks], b, acc1[t], 0, 0, 0);
            }
        }
        float mean[4], rstd[4];
#pragma unroll
        for (int r = 0; r < 4; ++r) {
            float s = acc1[0][r];
#pragma unroll
            for (int t = 1; t < 8; ++t) s += acc1[t][r];
            s += __shfl_xor(s, 1); s += __shfl_xor(s, 2);
            s += __shfl_xor(s, 4); s += __shfl_xor(s, 8);
            float m = s * (1.0f / 128.0f);
            float q = 0.f;
#pragma unroll
            for (int t = 0; t < 8; ++t) { float d = acc1[t][r] - m; q = fmaf(d, d, q); }
            q += __shfl_xor(q, 1); q += __shfl_xor(q, 2);
            q += __shfl_xor(q, 4); q += __shfl_xor(q, 8);
            mean[r] = m; rstd[r] = rsqrtf(q * (1.0f / 128.0f) + 1e-5f);
        }
#pragma unroll
        for (int r = 0; r < 4; ++r) {
            int rw = g * 4 + r;
            int swz = (rw & 7) << 3;
#pragma unroll
            for (int t = 0; t < 8; ++t) {
                float y = fmaf((acc1[t][r] - mean[r]) * rstd[r], g1v[t], t1v[t]);
                y = fmaxf(y, 0.f);
                Hl[rw * 128 + ((t * 16 + c) ^ swz)] = f2bf(y);
            }
        }
        bf16x8 a2[4];
        const int swzr = (c & 7) << 3;
#pragma unroll
        for (int ks = 0; ks < 4; ++ks)
            a2[ks] = *(const bf16x8*)(Hl + c * 128 + ((ks * 32 + g * 8) ^ swzr));

        f32x4 acc2[4];
#pragma unroll
        for (int t = 0; t < 4; ++t) { f32x4 z = {b2v[t], b2v[t], b2v[t], b2v[t]}; acc2[t] = z; }
#pragma unroll
        for (int ks = 0; ks < 4; ++ks) {
#pragma unroll
            for (int t = 0; t < 4; ++t) {
                bf16x8 b = *(const bf16x8*)(lds + 16384 + (ks * 4 + t) * 512 + l * 8);
                acc2[t] = __builtin_amdgcn_mfma_f32_16x16x32_bf16(a2[ks], b, acc2[t], 0, 0, 0);
            }
        }
        float logit[4];
#pragma unroll
        for (int r = 0; r < 4; ++r) {
            float s = acc2[0][r] + acc2[1][r] + acc2[2][r] + acc2[3][r];
            s += __shfl_xor(s, 1); s += __shfl_xor(s, 2);
            s += __shfl_xor(s, 4); s += __shfl_xor(s, 8);
            float m = s * (1.0f / 64.0f);
            float q = 0.f;
#pragma unroll
            for (int t = 0; t < 4; ++t) { float d = acc2[t][r] - m; q = fmaf(d, d, q); }
            q += __shfl_xor(q, 1); q += __shfl_xor(q, 2);
            q += __shfl_xor(q, 4); q += __shfl_xor(q, 8);
            float rs = rsqrtf(q * (1.0f / 64.0f) + 1e-5f);
            float p = 0.f;
#pragma unroll
            for (int t = 0; t < 4; ++t) {
                float y = fmaf((acc2[t][r] - m) * rs, g2v[t], t2v[t]);
                y = fmaxf(y, 0.f);
                p = fmaf(y, w3v[t], p);
            }
            p += __shfl_xor(p, 1); p += __shfl_xor(p, 2);
            p += __shfl_xor(p, 4); p += __shfl_xor(p, 8);
            logit[r] = p + b3v;
        }
        if (c < 4) {
            int e = tile * 16 + g * 4 + c;
            float lg = (c == 0) ? logit[0] : (c == 1) ? logit[1] : (c == 2) ? logit[2] : logit[3];
            float nz = noise[e];
            float z = __logf(nz) - log1pf(-nz) + lg;
            float gate = 1.0f / (1.0f + __expf(-z));
            int od = outd[src[e]]; if (od < 1) od = 1;
            int idg = ind[dst[e]]; if (idg < 1) idg = 1;
            out[e] = gate * (rsqrtf((float)od) * rsqrtf((float)idg));
        }
    }
}

// ---------------- launch ----------------

extern "C" void kernel_launch(void* const* d_in, const int* in_sizes, int n_in,
                              void* d_out, int out_size, void* d_ws, size_t ws_size,
                              hipStream_t stream) {
    const float* emb   = (const float*)d_in[0];
    const int*   src   = (const int*)  d_in[1];
    const int*   dst   = (const int*)  d_in[2];
    const float* noise = (const float*)d_in[3];
    const float* W1  = (const float*)d_in[4];
    const float* b1  = (const float*)d_in[5];
    const float* g1  = (const float*)d_in[6];
    const float* bt1 = (const float*)d_in[7];
    const float* W2  = (const float*)d_in[8];
    const float* b2  = (const float*)d_in[9];
    const float* g2  = (const float*)d_in[10];
    const float* bt2 = (const float*)d_in[11];
    const float* W3  = (const float*)d_in[12];
    const float* b3  = (const float*)d_in[13];

    char* ws = (char*)d_ws;
    const size_t NEED = 6400000 + IMG_B + 400000;

    if (ws_size >= NEED) {
        ushort* embB = (ushort*)ws;                       // 6,400,000 B
        char*   img  = ws + 6400000;                      // 50,432 B
        int* outd = (int*)(ws + 6400000 + IMG_B);
        int* ind  = outd + N_NODES;

        hipMemsetAsync(outd, 0, 2 * N_NODES * sizeof(int), stream);
        prep_hist<<<2048, 256, 0, stream>>>(emb, src, dst, W1, b1, g1, bt1,
                                            W2, b2, g2, bt2, W3,
                                            embB, img, outd, ind);
        edge_mlp32<<<768, 256, 0, stream>>>(embB, src, dst, noise, (const i32x4*)img,
                                            b3, outd, ind, (float*)d_out);
    } else {
        int* outd = (int*)ws;
        int* ind  = outd + N_NODES;
        hipMemsetAsync(outd, 0, 2 * N_NODES * sizeof(int), stream);
        degree_hist<<<(NE + 255) / 256, 256, 0, stream>>>(src, dst, outd, ind);
        edge_mlp_mfma<<<512, 256, 0, stream>>>(emb, src, dst, noise,
                                               W1, b1, g1, bt1,
                                               W2, b2, g2, bt2,
                                               W3, b3, outd, ind,
                                               (float*)d_out);
    }
}

// Round 7
// 150.431 us; speedup vs baseline: 1.0609x; 1.0373x over previous
//
#include <hip/hip_runtime.h>
#include <hip/hip_bf16.h>

#define N_NODES 50000
#define NE      800000
#define NT32    (NE / 32)
#define NTILES  (NE / 16)

typedef __attribute__((ext_vector_type(8)))  short bf16x8;
typedef __attribute__((ext_vector_type(4)))  float f32x4;
typedef __attribute__((ext_vector_type(16))) float f32x16;
typedef __attribute__((ext_vector_type(4)))  int   i32x4;
typedef __attribute__((ext_vector_type(2)))  int   i32x2;

static __device__ __forceinline__ short f2bf(float x) {
    union { float f; unsigned u; } v; v.f = x;
    unsigned r = (v.u + 0x7fffu + ((v.u >> 16) & 1u)) >> 16;  // RNE
    return (short)r;
}
static __device__ __forceinline__ float bflo(unsigned u) {
    union { unsigned u; float f; } v; v.u = u << 16; return v.f;
}
static __device__ __forceinline__ float bfhi(unsigned u) {
    union { unsigned u; float f; } v; v.u = u & 0xffff0000u; return v.f;
}
static __device__ __forceinline__ float bfs(unsigned short u) {
    union { unsigned u; float f; } v; v.u = ((unsigned)u) << 16; return v.f;
}
static __device__ __forceinline__ unsigned pk2bf(float a, float b) {
    union { __hip_bfloat162 h; unsigned u; } v;
    float2 f; f.x = a; f.y = b;
    v.h = __float22bfloat162_rn(f);
    return v.u;
}

// ---- workspace image layout (bytes from WF base) ----
#define OFF_W2   32768
#define OFF_B1   49152
#define OFF_B2   49408
#define OFF_GT1  49536
#define OFF_GT2  50048
#define OFF_W3   50304
#define IMG_B    50432
#define IMG_V4   (IMG_B / 16)   // 3152

// ---------------- fused prep: pack emb + weight images + degree hist ----------------

__global__ void prep_hist(const float* __restrict__ emb,
                          const int* __restrict__ src, const int* __restrict__ dst,
                          const float* __restrict__ W1, const float* __restrict__ b1,
                          const float* __restrict__ g1, const float* __restrict__ bt1,
                          const float* __restrict__ W2, const float* __restrict__ b2,
                          const float* __restrict__ g2, const float* __restrict__ bt2,
                          const float* __restrict__ W3,
                          ushort* __restrict__ embB, char* __restrict__ img,
                          int* __restrict__ outd, int* __restrict__ ind)
{
    const int i0 = blockIdx.x * 256 + threadIdx.x;
    const int n  = gridDim.x * 256;

    for (int t = i0; t < (N_NODES * 64 / 8); t += n) {
        const f32x4* p = (const f32x4*)(emb + (size_t)t * 8);
        f32x4 a = p[0], b = p[1];
        unsigned u0 = pk2bf(a[0], a[1]);
        unsigned u1 = pk2bf(a[2], a[3]);
        unsigned u2 = pk2bf(b[0], b[1]);
        unsigned u3 = pk2bf(b[2], b[3]);
        i32x4 o = {(int)u0, (int)u1, (int)u2, (int)u3};
        *(i32x4*)(embB + (size_t)t * 8) = o;
    }
    for (int t = i0; t < NE; t += n) {
        atomicAdd(outd + src[t], 1);
        atomicAdd(ind + dst[t], 1);
    }
    ushort* W1f = (ushort*)img;
    for (int t = i0; t < 16384; t += n) {
        int j = t & 7, lane = (t >> 3) & 63, f = t >> 9;
        int mt = f >> 3, ke = f & 7, h = lane >> 5, c = lane & 31;
        W1f[t] = f2bf(W1[(16 * ke + 8 * h + j) * 128 + 32 * mt + c]);
    }
    ushort* W2f = (ushort*)(img + OFF_W2);
    for (int t = i0; t < 8192; t += n) {
        int j = t & 7, lane = (t >> 3) & 63, f = t >> 9;
        int mt = f >> 3, ke = f & 7, h = lane >> 5, c = lane & 31;
        W2f[t] = f2bf(W2[(16 * ke + 8 * h + j) * 64 + 32 * mt + c]);
    }
    if (i0 < 128) ((ushort*)(img + OFF_B1))[i0] = f2bf(b1[i0]);
    if (i0 < 64)  ((ushort*)(img + OFF_B2))[i0] = f2bf(b2[i0]);
    if (i0 < 128) {
        int r4 = i0 & 3, h = (i0 >> 2) & 1, q4 = (i0 >> 3) & 3, mt = i0 >> 5;
        int f = 32 * mt + 8 * q4 + 4 * h + r4;
        ((unsigned*)(img + OFF_GT1))[i0] =
            (unsigned)(ushort)f2bf(g1[f]) | ((unsigned)(ushort)f2bf(bt1[f]) << 16);
    }
    if (i0 < 64) {
        int r4 = i0 & 3, h = (i0 >> 2) & 1, q4 = (i0 >> 3) & 3, mt = i0 >> 5;
        int f = 32 * mt + 8 * q4 + 4 * h + r4;
        ((unsigned*)(img + OFF_GT2))[i0] =
            (unsigned)(ushort)f2bf(g2[f]) | ((unsigned)(ushort)f2bf(bt2[f]) << 16);
        ((ushort*)(img + OFF_W3))[i0] = f2bf(W3[f]);
    }
}

// ---------------- main: 32x32x16 MFMA, transposed (features=M, edges=N) ----------------
// A (weights): lane l holds A[l&31][(l>>5)*8+j]
// B (data):    lane l holds B[(l>>5)*8+j][l&31]
// C: col=lane&31 (edge), row=(reg&3)+8*(reg>>2)+4*(lane>>5) (feature) [m74/m101]
// Register plan (R7): unified file; target <=168 total for 3 waves/SIMD.
// Only the 4 SRC frags (16 regs) are held across the epilogue (prefetched
// after b2-fold); the 4 DST frags load at loop top and are consumed at
// ke=4 (~256 cyc later -> L2 latency covered). L1 peak: acc(64)+frags(32).

__global__ __launch_bounds__(256, 3) void edge_mlp32(
    const ushort* __restrict__ embB,
    const int*   __restrict__ src, const int* __restrict__ dst,
    const float* __restrict__ noise,
    const i32x4* __restrict__ WFimg,
    const float* __restrict__ b3p,
    const int* __restrict__ outd, const int* __restrict__ ind,
    float* __restrict__ out)
{
    __shared__ i32x4 ldsv[IMG_V4];
    char* ldsb = (char*)ldsv;

    const int tid = threadIdx.x;
    for (int i = tid; i < IMG_V4; i += 256) ldsv[i] = WFimg[i];
    __syncthreads();

    const int l   = tid & 63;
    const int h   = l >> 5;
    const int c   = l & 31;

    const float b3v = b3p[0];

    bf16x8 bone = {};
    bone[0] = (h == 0) ? (short)0x3F80 : (short)0;

    const int gw = blockIdx.x * 4 + (tid >> 6);
    const int nw = gridDim.x * 4;

    // ---- pipeline prologue: indices + SRC fragments for first tile ----
    int sn, dn;
    bf16x8 fA0, fA1, fA2, fA3;
    {
        int t0 = (gw < NT32) ? gw : (NT32 - 1);
        int e0p = t0 * 32 + c;
        sn = src[e0p]; dn = dst[e0p];
        const ushort* sp = embB + (size_t)sn * 64;
        fA0 = *(const bf16x8*)(sp + 8 * h);
        fA1 = *(const bf16x8*)(sp + 16 + 8 * h);
        fA2 = *(const bf16x8*)(sp + 32 + 8 * h);
        fA3 = *(const bf16x8*)(sp + 48 + 8 * h);
    }

    for (int tile = gw; tile < NT32; tile += nw) {
        unsigned tz;
        asm volatile("v_mov_b32 %0, 0" : "=v"(tz));   // anti-LICM anchor
        const char* ldz = ldsb + tz;

        const int e0 = tile * 32 + c;

        // ---- loop top: DST frags for CURRENT tile + next indices + epilogue loads ----
        const ushort* dp = embB + (size_t)dn * 64;
        bf16x8 fD0 = *(const bf16x8*)(dp + 8 * h);
        bf16x8 fD1 = *(const bf16x8*)(dp + 16 + 8 * h);
        bf16x8 fD2 = *(const bf16x8*)(dp + 32 + 8 * h);
        bf16x8 fD3 = *(const bf16x8*)(dp + 48 + 8 * h);

        const int tn  = tile + nw;
        const int tcl = (tn < NT32) ? tn : tile;
        const int e0n = tcl * 32 + c;
        int snN = src[e0n];
        int dnN = dst[e0n];
        float nz = noise[e0];
        int odv = outd[sn];
        int idv = ind[dn];

        // ---- layer 1 MFMAs: ke 0..3 on src frags, 4..7 on dst frags ----
        const ushort* W1z = (const ushort*)ldz;
        f32x16 acc[4] = {};
#pragma unroll
        for (int ke = 0; ke < 4; ++ke) {
            bf16x8 bf = (ke == 0) ? fA0 : (ke == 1) ? fA1 : (ke == 2) ? fA2 : fA3;
#pragma unroll
            for (int mt = 0; mt < 4; ++mt) {
                bf16x8 w = *(const bf16x8*)(W1z + (mt * 8 + ke) * 512 + l * 8);
                acc[mt] = __builtin_amdgcn_mfma_f32_32x32x16_bf16(w, bf, acc[mt], 0, 0, 0);
            }
        }
#pragma unroll
        for (int ke = 4; ke < 8; ++ke) {
            bf16x8 bf = (ke == 4) ? fD0 : (ke == 5) ? fD1 : (ke == 6) ? fD2 : fD3;
#pragma unroll
            for (int mt = 0; mt < 4; ++mt) {
                bf16x8 w = *(const bf16x8*)(W1z + (mt * 8 + ke) * 512 + l * 8);
                acc[mt] = __builtin_amdgcn_mfma_f32_32x32x16_bf16(w, bf, acc[mt], 0, 0, 0);
            }
        }
        // b1 fold
        const ushort* b1z = (const ushort*)(ldz + OFF_B1);
#pragma unroll
        for (int mt = 0; mt < 4; ++mt) {
            bf16x8 w = {};
            short bv = b1z[32 * mt + c];
            w[0] = (h == 0) ? bv : (short)0;
            acc[mt] = __builtin_amdgcn_mfma_f32_32x32x16_bf16(w, bone, acc[mt], 0, 0, 0);
        }

        // ---- LN1 stats ----
        float s0 = 0.f, s1 = 0.f, q0 = 0.f, q1 = 0.f;
#pragma unroll
        for (int mt = 0; mt < 4; ++mt) {
#pragma unroll
            for (int i = 0; i < 16; i += 2) {
                float v0 = acc[mt][i], v1 = acc[mt][i + 1];
                s0 += v0; q0 = fmaf(v0, v0, q0);
                s1 += v1; q1 = fmaf(v1, v1, q1);
            }
        }
        float s = s0 + s1, q = q0 + q1;
        s += __shfl_xor(s, 32);
        q += __shfl_xor(q, 32);
        const float mu = s * (1.0f / 128.0f);
        const float rs = rsqrtf(q * (1.0f / 128.0f) - mu * mu + 1e-5f);
        const float c0 = -mu * rs;

        // ---- per-mt: LN1 apply+pack -> cross-h exchange -> layer-2 MFMAs ----
        const ushort* W2z = (const ushort*)(ldz + OFF_W2);
        f32x16 acc2[2] = {};
#pragma unroll
        for (int mt = 0; mt < 4; ++mt) {
            unsigned pk[4][2];
#pragma unroll
            for (int q4 = 0; q4 < 4; ++q4) {
                i32x4 pg = *(const i32x4*)(ldz + OFF_GT1 + ((mt * 4 + q4) * 2 + h) * 16);
                float t[4];
#pragma unroll
                for (int r4 = 0; r4 < 4; ++r4) {
                    unsigned u = (unsigned)pg[r4];
                    float v = acc[mt][q4 * 4 + r4];
                    float w = fmaf(v, rs, c0);
                    float y = fmaf(w, bflo(u), bfhi(u));
                    t[r4] = fmaxf(y, 0.f);
                }
                pk[q4][0] = pk2bf(t[0], t[1]);
                pk[q4][1] = pk2bf(t[2], t[3]);
            }
#pragma unroll
            for (int sub = 0; sub < 2; ++sub) {
                const int ke = 2 * mt + sub;
                const int qa = 2 * sub, qb = qa + 1;
                unsigned S0 = h ? pk[qa][0] : pk[qb][0];
                unsigned S1 = h ? pk[qa][1] : pk[qb][1];
                unsigned r0 = (unsigned)__shfl_xor((int)S0, 32);
                unsigned r1 = (unsigned)__shfl_xor((int)S1, 32);
                unsigned o0 = h ? pk[qb][0] : pk[qa][0];
                unsigned o1 = h ? pk[qb][1] : pk[qa][1];
                union { i32x4 i; bf16x8 b; } u;
                u.i[0] = (int)(h ? r0 : o0);
                u.i[1] = (int)(h ? r1 : o1);
                u.i[2] = (int)(h ? o0 : r0);
                u.i[3] = (int)(h ? o1 : r1);
#pragma unroll
                for (int mt2 = 0; mt2 < 2; ++mt2) {
                    bf16x8 w = *(const bf16x8*)(W2z + (mt2 * 8 + ke) * 512 + l * 8);
                    acc2[mt2] = __builtin_amdgcn_mfma_f32_32x32x16_bf16(w, u.b, acc2[mt2], 0, 0, 0);
                }
            }
        }
        const ushort* b2z = (const ushort*)(ldz + OFF_B2);
#pragma unroll
        for (int mt2 = 0; mt2 < 2; ++mt2) {
            bf16x8 w = {};
            short bv = b2z[32 * mt2 + c];
            w[0] = (h == 0) ? bv : (short)0;
            acc2[mt2] = __builtin_amdgcn_mfma_f32_32x32x16_bf16(w, bone, acc2[mt2], 0, 0, 0);
        }

        // ---- issue next-tile SRC gathers HERE: acc[] dead, only 16 regs held ----
        {
            const ushort* spn = embB + (size_t)snN * 64;
            fA0 = *(const bf16x8*)(spn + 8 * h);
            fA1 = *(const bf16x8*)(spn + 16 + 8 * h);
            fA2 = *(const bf16x8*)(spn + 32 + 8 * h);
            fA3 = *(const bf16x8*)(spn + 48 + 8 * h);
        }

        // ---- LN2 stats ----
        float t0 = 0.f, t1 = 0.f, p0 = 0.f, p1 = 0.f;
#pragma unroll
        for (int mt2 = 0; mt2 < 2; ++mt2) {
#pragma unroll
            for (int i = 0; i < 16; i += 2) {
                float v0 = acc2[mt2][i], v1 = acc2[mt2][i + 1];
                t0 += v0; p0 = fmaf(v0, v0, p0);
                t1 += v1; p1 = fmaf(v1, v1, p1);
            }
        }
        float s2 = t0 + t1, q2 = p0 + p1;
        s2 += __shfl_xor(s2, 32);
        q2 += __shfl_xor(q2, 32);
        const float mu2 = s2 * (1.0f / 64.0f);
        const float rs2 = rsqrtf(q2 * (1.0f / 64.0f) - mu2 * mu2 + 1e-5f);
        const float c02 = -mu2 * rs2;

        // ---- LN2 apply + relu + dot(W3) ----
        float lg = 0.f;
#pragma unroll
        for (int mt2 = 0; mt2 < 2; ++mt2) {
#pragma unroll
            for (int q4 = 0; q4 < 4; ++q4) {
                const int bse = (mt2 * 4 + q4) * 2 + h;
                i32x4 pg = *(const i32x4*)(ldz + OFF_GT2 + bse * 16);
                i32x2 wq = *(const i32x2*)(ldz + OFF_W3 + bse * 8);
#pragma unroll
                for (int r4 = 0; r4 < 4; ++r4) {
                    unsigned ug = (unsigned)pg[r4];
                    unsigned short uw = (unsigned short)(((unsigned)wq[r4 >> 1]) >> (16 * (r4 & 1)));
                    float v = acc2[mt2][q4 * 4 + r4];
                    float w = fmaf(v, rs2, c02);
                    float y = fmaf(w, bflo(ug), bfhi(ug));
                    y = fmaxf(y, 0.f);
                    lg = fmaf(y, bfs(uw), lg);
                }
            }
        }
        lg += __shfl_xor(lg, 32);
        lg += b3v;

        // ---- gate + degree norm (h==0 lanes) ----
        if (h == 0) {
            float z = __logf(nz) - log1pf(-nz) + lg;
            float gate = 1.0f / (1.0f + __expf(-z));
            int od = odv; if (od < 1) od = 1;
            int idg = idv; if (idg < 1) idg = 1;
            out[e0] = gate * (rsqrtf((float)od) * rsqrtf((float)idg));
        }

        sn = snN; dn = dnN;
    }
}

// ================= R2 fallback (validated) — used if ws too small =================

__global__ void degree_hist(const int* __restrict__ src, const int* __restrict__ dst,
                            int* __restrict__ outd, int* __restrict__ ind) {
    int i = blockIdx.x * 256 + threadIdx.x;
    if (i < NE) {
        atomicAdd(outd + src[i], 1);
        atomicAdd(ind + dst[i], 1);
    }
}

__global__ __launch_bounds__(256, 2) void edge_mlp_mfma(
    const float* __restrict__ emb,
    const int*   __restrict__ src, const int* __restrict__ dst,
    const float* __restrict__ noise,
    const float* __restrict__ W1, const float* __restrict__ b1,
    const float* __restrict__ g1, const float* __restrict__ bt1,
    const float* __restrict__ W2, const float* __restrict__ b2,
    const float* __restrict__ g2, const float* __restrict__ bt2,
    const float* __restrict__ W3, const float* __restrict__ b3,
    const int*   __restrict__ outd, const int* __restrict__ ind,
    float* __restrict__ out)
{
    __shared__ short lds[32768];
    const int tid = threadIdx.x;
    const int wid = tid >> 6;
    const int l   = tid & 63;
    const int g   = l >> 4;
    const int c   = l & 15;

    for (int i = tid; i < 16384; i += 256) {
        int j = i & 7, lane = (i >> 3) & 63, p = i >> 9;
        int ks = p >> 3, t = p & 7;
        int row = ks * 32 + (lane >> 4) * 8 + j;
        int col = t * 16 + (lane & 15);
        lds[i] = f2bf(W1[row * 128 + col]);
    }
    for (int i = tid; i < 8192; i += 256) {
        int j = i & 7, lane = (i >> 3) & 63, p = i >> 9;
        int ks = p >> 2, t = p & 3;
        int row = ks * 32 + (lane >> 4) * 8 + j;
        int col = t * 16 + (lane & 15);
        lds[16384 + i] = f2bf(W2[row * 64 + col]);
    }
    __syncthreads();

    short* Hl = lds + 24576 + wid * 2048;
    float b1v[8], g1v[8], t1v[8];
#pragma unroll
    for (int t = 0; t < 8; ++t) { int f = t * 16 + c; b1v[t] = b1[f]; g1v[t] = g1[f]; t1v[t] = bt1[f]; }
    float b2v[4], g2v[4], t2v[4], w3v[4];
#pragma unroll
    for (int t = 0; t < 4; ++t) { int f = t * 16 + c; b2v[t] = b2[f]; g2v[t] = g2[f]; t2v[t] = bt2[f]; w3v[t] = W3[f]; }
    const float b3v = b3[0];

    const int gw = blockIdx.x * 4 + wid;
    const int nw = gridDim.x * 4;

    for (int tile = gw; tile < NTILES; tile += nw) {
        const int e0 = tile * 16 + c;
        const int sn = src[e0], dn = dst[e0];
        const f32x4* sp = (const f32x4*)(emb + (size_t)sn * 64);
        const f32x4* dp = (const f32x4*)(emb + (size_t)dn * 64);
        f32x4 u[8];
        u[0] = sp[2 * g]; u[1] = sp[2 * g + 1];
        u[2] = sp[8 + 2 * g]; u[3] = sp[8 + 2 * g + 1];
        u[4] = dp[2 * g]; u[5] = dp[2 * g + 1];
        u[6] = dp[8 + 2 * g]; u[7] = dp[8 + 2 * g + 1];

        bf16x8 a1[4];
#pragma unroll
        for (int ks = 0; ks < 4; ++ks) {
            f32x4 x0 = u[2 * ks], x1 = u[2 * ks + 1];
            bf16x8 a;
            a[0] = f2bf(x0[0]); a[1] = f2bf(x0[1]); a[2] = f2bf(x0[2]); a[3] = f2bf(x0[3]);
            a[4] = f2bf(x1[0]); a[5] = f2bf(x1[1]); a[6] = f2bf(x1[2]); a[7] = f2bf(x1[3]);
            a1[ks] = a;
        }
        f32x4 acc1[8];
#pragma unroll
        for (int t = 0; t < 8; ++t) { f32x4 z = {b1v[t], b1v[t], b1v[t], b1v[t]}; acc1[t] = z; }
#pragma unroll
        for (int ks = 0; ks < 4; ++ks) {
#pragma unroll
            for (int t = 0; t < 8; ++t) {
                bf16x8 b = *(const bf16x8*)(lds + (ks * 8 + t) * 512 + l * 8);
                acc1[t] = __builtin_amdgcn_mfma_f32_16x16x32_bf16(a1[ks], b, acc1[t], 0, 0, 0);
            }
        }
        float mean[4], rstd[4];
#pragma unroll
        for (int r = 0; r < 4; ++r) {
            float s = acc1[0][r];
#pragma unroll
            for (int t = 1; t < 8; ++t) s += acc1[t][r];
            s += __shfl_xor(s, 1); s += __shfl_xor(s, 2);
            s += __shfl_xor(s, 4); s += __shfl_xor(s, 8);
            float m = s * (1.0f / 128.0f);
            float q = 0.f;
#pragma unroll
            for (int t = 0; t < 8; ++t) { float d = acc1[t][r] - m; q = fmaf(d, d, q); }
            q += __shfl_xor(q, 1); q += __shfl_xor(q, 2);
            q += __shfl_xor(q, 4); q += __shfl_xor(q, 8);
            mean[r] = m; rstd[r] = rsqrtf(q * (1.0f / 128.0f) + 1e-5f);
        }
#pragma unroll
        for (int r = 0; r < 4; ++r) {
            int rw = g * 4 + r;
            int swz = (rw & 7) << 3;
#pragma unroll
            for (int t = 0; t < 8; ++t) {
                float y = fmaf((acc1[t][r] - mean[r]) * rstd[r], g1v[t], t1v[t]);
                y = fmaxf(y, 0.f);
                Hl[rw * 128 + ((t * 16 + c) ^ swz)] = f2bf(y);
            }
        }
        bf16x8 a2[4];
        const int swzr = (c & 7) << 3;
#pragma unroll
        for (int ks = 0; ks < 4; ++ks)
            a2[ks] = *(const bf16x8*)(Hl + c * 128 + ((ks * 32 + g * 8) ^ swzr));

        f32x4 acc2[4];
#pragma unroll
        for (int t = 0; t < 4; ++t) { f32x4 z = {b2v[t], b2v[t], b2v[t], b2v[t]}; acc2[t] = z; }
#pragma unroll
        for (int ks = 0; ks < 4; ++ks) {
#pragma unroll
            for (int t = 0; t < 4; ++t) {
                bf16x8 b = *(const bf16x8*)(lds + 16384 + (ks * 4 + t) * 512 + l * 8);
                acc2[t] = __builtin_amdgcn_mfma_f32_16x16x32_bf16(a2[ks], b, acc2[t], 0, 0, 0);
            }
        }
        float logit[4];
#pragma unroll
        for (int r = 0; r < 4; ++r) {
            float s = acc2[0][r] + acc2[1][r] + acc2[2][r] + acc2[3][r];
            s += __shfl_xor(s, 1); s += __shfl_xor(s, 2);
            s += __shfl_xor(s, 4); s += __shfl_xor(s, 8);
            float m = s * (1.0f / 64.0f);
            float q = 0.f;
#pragma unroll
            for (int t = 0; t < 4; ++t) { float d = acc2[t][r] - m; q = fmaf(d, d, q); }
            q += __shfl_xor(q, 1); q += __shfl_xor(q, 2);
            q += __shfl_xor(q, 4); q += __shfl_xor(q, 8);
            float rs = rsqrtf(q * (1.0f / 64.0f) + 1e-5f);
            float p = 0.f;
#pragma unroll
            for (int t = 0; t < 4; ++t) {
                float y = fmaf((acc2[t][r] - m) * rs, g2v[t], t2v[t]);
                y = fmaxf(y, 0.f);
                p = fmaf(y, w3v[t], p);
            }
            p += __shfl_xor(p, 1); p += __shfl_xor(p, 2);
            p += __shfl_xor(p, 4); p += __shfl_xor(p, 8);
            logit[r] = p + b3v;
        }
        if (c < 4) {
            int e = tile * 16 + g * 4 + c;
            float lg = (c == 0) ? logit[0] : (c == 1) ? logit[1] : (c == 2) ? logit[2] : logit[3];
            float nz = noise[e];
            float z = __logf(nz) - log1pf(-nz) + lg;
            float gate = 1.0f / (1.0f + __expf(-z));
            int od = outd[src[e]]; if (od < 1) od = 1;
            int idg = ind[dst[e]]; if (idg < 1) idg = 1;
            out[e] = gate * (rsqrtf((float)od) * rsqrtf((float)idg));
        }
    }
}

// ---------------- launch ----------------

extern "C" void kernel_launch(void* const* d_in, const int* in_sizes, int n_in,
                              void* d_out, int out_size, void* d_ws, size_t ws_size,
                              hipStream_t stream) {
    const float* emb   = (const float*)d_in[0];
    const int*   src   = (const int*)  d_in[1];
    const int*   dst   = (const int*)  d_in[2];
    const float* noise = (const float*)d_in[3];
    const float* W1  = (const float*)d_in[4];
    const float* b1  = (const float*)d_in[5];
    const float* g1  = (const float*)d_in[6];
    const float* bt1 = (const float*)d_in[7];
    const float* W2  = (const float*)d_in[8];
    const float* b2  = (const float*)d_in[9];
    const float* g2  = (const float*)d_in[10];
    const float* bt2 = (const float*)d_in[11];
    const float* W3  = (const float*)d_in[12];
    const float* b3  = (const float*)d_in[13];

    char* ws = (char*)d_ws;
    const size_t NEED = 6400000 + IMG_B + 400000;

    if (ws_size >= NEED) {
        ushort* embB = (ushort*)ws;                       // 6,400,000 B
        char*   img  = ws + 6400000;                      // 50,432 B
        int* outd = (int*)(ws + 6400000 + IMG_B);
        int* ind  = outd + N_NODES;

        hipMemsetAsync(outd, 0, 2 * N_NODES * sizeof(int), stream);
        prep_hist<<<2048, 256, 0, stream>>>(emb, src, dst, W1, b1, g1, bt1,
                                            W2, b2, g2, bt2, W3,
                                            embB, img, outd, ind);
        edge_mlp32<<<768, 256, 0, stream>>>(embB, src, dst, noise, (const i32x4*)img,
                                            b3, outd, ind, (float*)d_out);
    } else {
        int* outd = (int*)ws;
        int* ind  = outd + N_NODES;
        hipMemsetAsync(outd, 0, 2 * N_NODES * sizeof(int), stream);
        degree_hist<<<(NE + 255) / 256, 256, 0, stream>>>(src, dst, outd, ind);
        edge_mlp_mfma<<<512, 256, 0, stream>>>(emb, src, dst, noise,
                                               W1, b1, g1, bt1,
                                               W2, b2, g2, bt2,
                                               W3, b3, outd, ind,
                                               (float*)d_out);
    }
}